// Round 6
// baseline (603.572 us; speedup 1.0000x reference)
//
#include <hip/hip_runtime.h>
#include <cstdint>
#include <cstddef>

// Problem constants (B=4, S=4096, D=1024, Din=2048)
#define BB 4
#define SS 4096
#define DD 1024
#define DIN 2048
#define MTOT (BB*SS)        // 16384 rows
#define K1 DD               // GEMM1 K = 1024
#define K2 DIN              // GEMM2 K = 2048
#define N2 DD               // GEMM2 N = 1024
#define NCH (BB*DIN)        // 8192 scan channels
#define NCHUNK 32
#define CLEN (SS/NCHUNK)    // 128

typedef _Float16 half8  __attribute__((ext_vector_type(8)));
typedef _Float16 half4v __attribute__((ext_vector_type(4)));
typedef float    floatx4 __attribute__((ext_vector_type(4)));

#define AS1(p) ((__attribute__((address_space(1))) void*)(uintptr_t)(p))
#define AS3(p) ((__attribute__((address_space(3))) void*)(uint32_t)(uintptr_t)(p))

__device__ __forceinline__ void gload16(const void* g, void* l) {
  // async global->LDS, 16B/lane; LDS dest = wave-uniform base + lane*16
  __builtin_amdgcn_global_load_lds(AS1(g), AS3(l), 16, 0, 0);
}

__device__ __forceinline__ float sigm(float x) { return 1.f / (1.f + __expf(-x)); }
__device__ __forceinline__ uint32_t hbits(float f) {
  _Float16 h = (_Float16)f; uint16_t u; __builtin_memcpy(&u, &h, 2); return (uint32_t)u;
}
__device__ __forceinline__ float h_lo(uint32_t v) {
  uint16_t u = (uint16_t)(v & 0xffffu); _Float16 h; __builtin_memcpy(&h, &u, 2); return (float)h;
}
__device__ __forceinline__ float h_hi(uint32_t v) {
  uint16_t u = (uint16_t)(v >> 16); _Float16 h; __builtin_memcpy(&h, &u, 2); return (float)h;
}

// ---------------- elementwise converts ----------------

__global__ void f32_to_f16_vec(const float* __restrict__ src, _Float16* __restrict__ dst) {
  int i = (blockIdx.x * blockDim.x + threadIdx.x) * 4;
  float4 v = *(const float4*)(src + i);
  half4v o; o.x = (_Float16)v.x; o.y = (_Float16)v.y; o.z = (_Float16)v.z; o.w = (_Float16)v.w;
  *(half4v*)(dst + i) = o;
}

// src[R][C] f32 -> dst[C][R] f16
__global__ void transpose_cvt(const float* __restrict__ src, _Float16* __restrict__ dst,
                              int R, int C) {
  __shared__ float t[32][33];
  int c0 = blockIdx.x * 32, r0 = blockIdx.y * 32;
  int tx = threadIdx.x, ty = threadIdx.y;
#pragma unroll
  for (int j = 0; j < 32; j += 8)
    t[ty + j][tx] = src[(size_t)(r0 + ty + j) * C + c0 + tx];
  __syncthreads();
#pragma unroll
  for (int j = 0; j < 32; j += 8)
    dst[(size_t)(c0 + ty + j) * R + r0 + tx] = (_Float16)t[tx][ty + j];
}

// ---------------- GEMM1: x @ W1 fused with gate math ----------------
// r6: occupancy was VGPR-bound, not LDS-bound (r5: 48KB LDS still 22% occ;
// arch 124 + acc 96 = ~220/wave -> 2 waves/SIMD of the 512-reg pool).
// Fix: 64-row block tile, wave tile 32x32x3 -> acc 48 regs, frags 32,
// __launch_bounds__(256,4) pins total <=128 -> 4 waves/SIMD, and LDS 36KB
// -> 4 blocks/CU (144KB). 2x waves vs r5.
//
// Asymmetric ring (proven r5):
//   A: ring-3 (3 x 4KB), prefetch distance 2  (xh streams from HBM)
//   B: ring-2 (2 x 12KB), prefetch distance 1 (w1t 12MB, L2/L3-hot)
// Per step t: [wait vmcnt(1)] [barrier] [stage B(t+1) x3, A(t+2) x1]
// [ds_read tile t] [12 MFMA]. At the wait, outstanding (oldest first) =
// A(t), B(t) x3, A(t+1): vmcnt(1) completes A(t)/B(t), leaves A(t+1) in
// flight (A keeps 2-period lead, B 1-period). WAR-safe: stage targets hold
// tile t-1 whose LDS reads all completed before their waves' barrier-t
// arrival. Tail steps issue dummy loads into adjacent ws buffers
// (branch-free, constant vmcnt; targeted bufs never read again).
//
// LDS swizzle: per-row k-group XOR swz(r)=(r>>1)&3 on the GLOBAL source
// address (gload_lds dest linear); conflict-free b128 reads (r2: conflicts=0).
// Block order: NATURAL raster (r2: XCD remap tripled HBM FETCH).
__global__ __launch_bounds__(256, 4) void gemm1_fused(
    const _Float16* __restrict__ xh, const _Float16* __restrict__ w1t,
    const float* __restrict__ b1, uint32_t* __restrict__ zg) {
  __shared__ _Float16 As[3][64 * 32];       // 3 x 4KB  = 12KB
  __shared__ _Float16 Bs[2][3][64 * 32];    // 2 x 12KB = 24KB ; 36KB total

  const int tid = threadIdx.x;
  const int wave = tid >> 6, lane = tid & 63;
  const int wm = wave >> 1, wn = wave & 1;     // 2x2 waves: 32 rows x 32 cols/gate
  const int m0 = blockIdx.y * 64;
  const int d0 = blockIdx.x * 64;
  const int lrow = lane >> 2;                              // staged row in 16-row chunk
  const int lk = (((lane & 3) ^ ((lrow >> 1) & 3)) * 8);   // staged k offset (halfs)
  const int roff = ((((lane & 15) << 2) | ((lane >> 4) ^ ((lane >> 1) & 3))) * 8); // read offset

  const _Float16* pA0 = xh + (size_t)(m0 + wave * 16 + lrow) * K1 + lk;
  const _Float16* pB0 = w1t + (size_t)(d0 + wave * 16 + lrow) * K1 + lk;
  const _Float16* pB1 = pB0 + (size_t)DIN * K1;
  const _Float16* pB2 = pB1 + (size_t)DIN * K1;

  floatx4 acc[3][2][2] = {};

  // prologue: B(0) x3, A(0), A(1)  (5 outstanding)
  gload16(pB0, &Bs[0][0][wave * 512]);
  gload16(pB1, &Bs[0][1][wave * 512]);
  gload16(pB2, &Bs[0][2][wave * 512]);
  gload16(pA0, &As[0][wave * 512]);
  gload16(pA0 + 32, &As[1][wave * 512]);
  pB0 += 32; pB1 += 32; pB2 += 32;   // -> tile 1
  pA0 += 64;                          // -> tile 2

#define G1_STEP(rbA, sbA, rbB, sbB)                                             \
  do {                                                                          \
    asm volatile("s_waitcnt vmcnt(1)" ::: "memory");                            \
    __builtin_amdgcn_s_barrier();                                               \
    asm volatile("" ::: "memory");                                              \
    gload16(pB0, &Bs[sbB][0][wave * 512]);                                      \
    gload16(pB1, &Bs[sbB][1][wave * 512]);                                      \
    gload16(pB2, &Bs[sbB][2][wave * 512]);                                      \
    gload16(pA0, &As[sbA][wave * 512]);                                         \
    pA0 += 32; pB0 += 32; pB1 += 32; pB2 += 32;                                 \
    half8 af[2], bfr[3][2];                                                     \
    _Pragma("unroll")                                                           \
    for (int mi = 0; mi < 2; ++mi)                                              \
      af[mi] = *(const half8*)(&As[rbA][(wm * 2 + mi) * 512 + roff]);           \
    _Pragma("unroll")                                                           \
    for (int gt = 0; gt < 3; ++gt)                                              \
      _Pragma("unroll")                                                         \
      for (int ni = 0; ni < 2; ++ni)                                            \
        bfr[gt][ni] = *(const half8*)(&Bs[rbB][gt][(wn * 2 + ni) * 512 + roff]);\
    _Pragma("unroll")                                                           \
    for (int gt = 0; gt < 3; ++gt)                                              \
      _Pragma("unroll")                                                         \
      for (int mi = 0; mi < 2; ++mi)                                            \
        _Pragma("unroll")                                                       \
        for (int ni = 0; ni < 2; ++ni)                                          \
          acc[gt][mi][ni] = __builtin_amdgcn_mfma_f32_16x16x32_f16(             \
              af[mi], bfr[gt][ni], acc[gt][mi][ni], 0, 0, 0);                   \
  } while (0)

  // 32 K-tiles; tile t reads As[t%3], Bs[t&1]; stages A(t+2)->(t+2)%3,
  // B(t+1)->(t+1)&1. Pattern period lcm(3,2)=6; 32 = 5*6 + 2.
  for (int it6 = 0; it6 < 5; ++it6) {
    G1_STEP(0, 2, 0, 1);
    G1_STEP(1, 0, 1, 0);
    G1_STEP(2, 1, 0, 1);
    G1_STEP(0, 2, 1, 0);
    G1_STEP(1, 0, 0, 1);
    G1_STEP(2, 1, 1, 0);
  }
  G1_STEP(0, 2, 0, 1);   // t=30
  G1_STEP(1, 0, 1, 0);   // t=31
#undef G1_STEP

  // epilogue: bias + gate math, write packed (z,g)
  // z = sigma(softplus(-f)-softplus(-i)) = u/(u+v), u=1+e^-f, v=1+e^-i
#pragma unroll
  for (int ni = 0; ni < 2; ++ni) {
    int d = d0 + wn * 32 + ni * 16 + (lane & 15);
    float bh = b1[d], bf_ = b1[DIN + d], bi = b1[2 * DIN + d];
#pragma unroll
    for (int mi = 0; mi < 2; ++mi) {
#pragma unroll
      for (int r = 0; r < 4; ++r) {
        int m = m0 + wm * 32 + mi * 16 + (lane >> 4) * 4 + r;
        float hv = acc[0][mi][ni][r] + bh;
        float fv = acc[1][mi][ni][r] + bf_;
        float iv = acc[2][mi][ni][r] + bi;
        float u = 1.f + __expf(-fminf(fmaxf(fv, -30.f), 30.f));
        float v = 1.f + __expf(-fminf(fmaxf(iv, -30.f), 30.f));
        float z = __fdividef(u, u + v);
        float gg = (hv >= 0.f) ? (hv + 0.5f)
                               : __fdividef(1.f, 1.f + __expf(-fmaxf(hv, -30.f)));
        zg[(size_t)m * DIN + d] = hbits(z) | (hbits(gg) << 16);
      }
    }
  }
}

// ---------------- chunked parallel scan: h_t = (1-z) h + z g ----------------

__global__ void scanA(const uint32_t* __restrict__ zg,
                      float* __restrict__ cA, float* __restrict__ cB) {
  int gidx = blockIdx.x * 256 + threadIdx.x;
  int q = gidx >> 13, c = gidx & (NCH - 1);
  int b = c >> 11, d = c & (DIN - 1);
  size_t base = ((size_t)b * SS + q * CLEN) * DIN + d;
  float A = 1.f, Bv = 0.f;
#pragma unroll 4
  for (int t = 0; t < CLEN; ++t) {
    uint32_t v = zg[base + (size_t)t * DIN];
    float z = h_lo(v), g = h_hi(v);
    A *= (1.f - z);
    Bv = fmaf(z, g - Bv, Bv);
  }
  cA[q * NCH + c] = A;
  cB[q * NCH + c] = Bv;
}

__global__ void scanB(const float* __restrict__ cA, const float* __restrict__ cB,
                      const float* __restrict__ init_h, float* __restrict__ cH) {
  int c = blockIdx.x * 256 + threadIdx.x;  // 8192 channels
  int d = c & (DIN - 1);
  float x = init_h[d];
  float h = (x >= 0.f) ? (x + 0.5f) : sigm(x);  // h0 = g(init_h)
#pragma unroll
  for (int q = 0; q < NCHUNK; ++q) {
    cH[q * NCH + c] = h;                        // h at START of chunk q
    h = fmaf(cA[q * NCH + c], h, cB[q * NCH + c]);
  }
}

__global__ void scanC(const uint32_t* __restrict__ zg, const float* __restrict__ cH,
                      _Float16* __restrict__ hh, float* __restrict__ out_tail) {
  int gidx = blockIdx.x * 256 + threadIdx.x;
  int q = gidx >> 13, c = gidx & (NCH - 1);
  int b = c >> 11, d = c & (DIN - 1);
  size_t base = ((size_t)b * SS + q * CLEN) * DIN + d;
  float h = cH[q * NCH + c];
#pragma unroll 4
  for (int t = 0; t < CLEN; ++t) {
    uint32_t v = zg[base + (size_t)t * DIN];
    float z = h_lo(v), g = h_hi(v);
    h = fmaf(z, g - h, h);
    hh[base + (size_t)t * DIN] = (_Float16)h;
  }
  if (q == NCHUNK - 1) {
    out_tail[c] = h;             // next_hidden
    out_tail[NCH + c] = logf(h); // next_log_hidden
  }
}

// ---------------- GEMM2: out_h @ W2 + b2 (128x128, ring-2) -----------------
// Ring-2 both sides: 32KB LDS. Distance-1 prefetch => vmcnt(0) at the wait,
// but those loads are a full K-step old. __launch_bounds__(256,4).
// Natural raster order (see gemm1 comment). Unchanged from r5.
__global__ __launch_bounds__(256, 4) void gemm2k(
    const _Float16* __restrict__ hh, const _Float16* __restrict__ w2t,
    const float* __restrict__ b2, float* __restrict__ out) {
  __shared__ _Float16 As[2][128 * 32];   // 2 x 8KB
  __shared__ _Float16 Bs[2][128 * 32];   // 2 x 8KB ; 32KB total

  const int tid = threadIdx.x;
  const int wave = tid >> 6, lane = tid & 63;
  const int wm = wave >> 1, wn = wave & 1;     // 2x2 waves: 64x64 each
  const int m0 = blockIdx.y * 128;
  const int n0 = blockIdx.x * 128;
  const int lrow = lane >> 2;
  const int lk = (((lane & 3) ^ ((lrow >> 1) & 3)) * 8);   // conflict-free swz (see gemm1)
  const int roff = ((((lane & 15) << 2) | ((lane >> 4) ^ ((lane >> 1) & 3))) * 8);

  const _Float16* pA0 = hh + (size_t)(m0 + (wave * 2 + 0) * 16 + lrow) * K2 + lk;
  const _Float16* pA1 = pA0 + (size_t)16 * K2;
  const _Float16* pB0 = w2t + (size_t)(n0 + (wave * 2 + 0) * 16 + lrow) * K2 + lk;
  const _Float16* pB1 = pB0 + (size_t)16 * K2;

  floatx4 acc[4][4] = {};

  // prologue: stage tile 0 into buf 0
  gload16(pA0, &As[0][(wave * 2 + 0) * 512]);
  gload16(pA1, &As[0][(wave * 2 + 1) * 512]);
  gload16(pB0, &Bs[0][(wave * 2 + 0) * 512]);
  gload16(pB1, &Bs[0][(wave * 2 + 1) * 512]);
  pA0 += 32; pA1 += 32; pB0 += 32; pB1 += 32;

#define G2_STEP(rb, sb)                                                         \
  do {                                                                          \
    asm volatile("s_waitcnt vmcnt(0)" ::: "memory");                            \
    __builtin_amdgcn_s_barrier();                                               \
    asm volatile("" ::: "memory");                                              \
    gload16(pA0, &As[sb][(wave * 2 + 0) * 512]);                                \
    gload16(pA1, &As[sb][(wave * 2 + 1) * 512]);                                \
    gload16(pB0, &Bs[sb][(wave * 2 + 0) * 512]);                                \
    gload16(pB1, &Bs[sb][(wave * 2 + 1) * 512]);                                \
    pA0 += 32; pA1 += 32; pB0 += 32; pB1 += 32;                                 \
    half8 af[4], bfr[4];                                                        \
    _Pragma("unroll")                                                           \
    for (int mi = 0; mi < 4; ++mi)                                              \
      af[mi] = *(const half8*)(&As[rb][(wm * 4 + mi) * 512 + roff]);            \
    _Pragma("unroll")                                                           \
    for (int ni = 0; ni < 4; ++ni)                                              \
      bfr[ni] = *(const half8*)(&Bs[rb][(wn * 4 + ni) * 512 + roff]);           \
    _Pragma("unroll")                                                           \
    for (int mi = 0; mi < 4; ++mi)                                              \
      _Pragma("unroll")                                                         \
      for (int ni = 0; ni < 4; ++ni)                                            \
        acc[mi][ni] = __builtin_amdgcn_mfma_f32_16x16x32_f16(                   \
            af[mi], bfr[ni], acc[mi][ni], 0, 0, 0);                             \
  } while (0)

  // 64 K-tiles; tile t reads buf t&1, stages t+1 -> (t+1)&1
  for (int it2 = 0; it2 < 32; ++it2) {
    G2_STEP(0, 1);
    G2_STEP(1, 0);
  }
#undef G2_STEP

#pragma unroll
  for (int ni = 0; ni < 4; ++ni) {
    int n = n0 + wn * 64 + ni * 16 + (lane & 15);
    float bias = b2[n];
#pragma unroll
    for (int mi = 0; mi < 4; ++mi) {
#pragma unroll
      for (int r = 0; r < 4; ++r) {
        int m = m0 + wm * 64 + mi * 16 + (lane >> 4) * 4 + r;
        out[(size_t)m * N2 + n] = acc[mi][ni][r] + bias;
      }
    }
  }
}

// ---------------- launch ----------------

extern "C" void kernel_launch(void* const* d_in, const int* in_sizes, int n_in,
                              void* d_out, int out_size, void* d_ws, size_t ws_size,
                              hipStream_t stream) {
  const float* x      = (const float*)d_in[0];
  const float* W1     = (const float*)d_in[1];
  const float* b1     = (const float*)d_in[2];
  const float* W2     = (const float*)d_in[3];
  const float* b2     = (const float*)d_in[4];
  const float* init_h = (const float*)d_in[5];
  float* out = (float*)d_out;

  char* w = (char*)d_ws;
  _Float16* xh  = (_Float16*)w; w += (size_t)MTOT * K1 * 2;       // 32 MB
  _Float16* w1t = (_Float16*)w; w += (size_t)3 * DIN * K1 * 2;    // 12 MB
  _Float16* w2t = (_Float16*)w; w += (size_t)N2 * K2 * 2;         // 4 MB
  uint32_t* zg  = (uint32_t*)w; w += (size_t)MTOT * DIN * 4;      // 128 MB
  _Float16* hh  = (_Float16*)w; w += (size_t)MTOT * DIN * 2;      // 64 MB
  float* cA = (float*)w; w += (size_t)NCH * NCHUNK * 4;
  float* cB = (float*)w; w += (size_t)NCH * NCHUNK * 4;
  float* cH = (float*)w; w += (size_t)NCH * NCHUNK * 4;

  f32_to_f16_vec<<<dim3(MTOT * K1 / 1024), dim3(256), 0, stream>>>(x, xh);
  transpose_cvt<<<dim3(3 * DIN / 32, K1 / 32), dim3(32, 8), 0, stream>>>(W1, w1t, K1, 3 * DIN);
  transpose_cvt<<<dim3(N2 / 32, K2 / 32), dim3(32, 8), 0, stream>>>(W2, w2t, K2, N2);

  gemm1_fused<<<dim3(DIN / 64, MTOT / 64), dim3(256), 0, stream>>>(xh, w1t, b1, zg);

  scanA<<<dim3(NCH * NCHUNK / 256), dim3(256), 0, stream>>>(zg, cA, cB);
  scanB<<<dim3(NCH / 256), dim3(256), 0, stream>>>(cA, cB, init_h, cH);
  scanC<<<dim3(NCH * NCHUNK / 256), dim3(256), 0, stream>>>(zg, cH, hh, out + (size_t)MTOT * DD);

  gemm2k<<<dim3(N2 / 128, MTOT / 128), dim3(256), 0, stream>>>(hh, w2t, b2, out);
}

// Round 7
// 541.058 us; speedup vs baseline: 1.1155x; 1.1155x over previous
//
#include <hip/hip_runtime.h>
#include <cstdint>
#include <cstddef>

// Problem constants (B=4, S=4096, D=1024, Din=2048)
#define BB 4
#define SS 4096
#define DD 1024
#define DIN 2048
#define MTOT (BB*SS)        // 16384 rows
#define K1 DD               // GEMM1 K = 1024
#define K2 DIN              // GEMM2 K = 2048
#define N2 DD               // GEMM2 N = 1024
#define NCH (BB*DIN)        // 8192 scan channels
#define NCHUNK 32
#define CLEN (SS/NCHUNK)    // 128

typedef _Float16 half8  __attribute__((ext_vector_type(8)));
typedef _Float16 half4v __attribute__((ext_vector_type(4)));
typedef float    floatx4 __attribute__((ext_vector_type(4)));

#define AS1(p) ((__attribute__((address_space(1))) void*)(uintptr_t)(p))
#define AS3(p) ((__attribute__((address_space(3))) void*)(uint32_t)(uintptr_t)(p))

__device__ __forceinline__ void gload16(const void* g, void* l) {
  // async global->LDS, 16B/lane; LDS dest = wave-uniform base + lane*16
  __builtin_amdgcn_global_load_lds(AS1(g), AS3(l), 16, 0, 0);
}

__device__ __forceinline__ float sigm(float x) { return 1.f / (1.f + __expf(-x)); }
__device__ __forceinline__ uint32_t hbits(float f) {
  _Float16 h = (_Float16)f; uint16_t u; __builtin_memcpy(&u, &h, 2); return (uint32_t)u;
}
__device__ __forceinline__ float h_lo(uint32_t v) {
  uint16_t u = (uint16_t)(v & 0xffffu); _Float16 h; __builtin_memcpy(&h, &u, 2); return (float)h;
}
__device__ __forceinline__ float h_hi(uint32_t v) {
  uint16_t u = (uint16_t)(v >> 16); _Float16 h; __builtin_memcpy(&h, &u, 2); return (float)h;
}

// ---------------- elementwise converts ----------------

__global__ void f32_to_f16_vec(const float* __restrict__ src, _Float16* __restrict__ dst) {
  int i = (blockIdx.x * blockDim.x + threadIdx.x) * 4;
  float4 v = *(const float4*)(src + i);
  half4v o; o.x = (_Float16)v.x; o.y = (_Float16)v.y; o.z = (_Float16)v.z; o.w = (_Float16)v.w;
  *(half4v*)(dst + i) = o;
}

// src[R][C] f32 -> dst[C][R] f16
__global__ void transpose_cvt(const float* __restrict__ src, _Float16* __restrict__ dst,
                              int R, int C) {
  __shared__ float t[32][33];
  int c0 = blockIdx.x * 32, r0 = blockIdx.y * 32;
  int tx = threadIdx.x, ty = threadIdx.y;
#pragma unroll
  for (int j = 0; j < 32; j += 8)
    t[ty + j][tx] = src[(size_t)(r0 + ty + j) * C + c0 + tx];
  __syncthreads();
#pragma unroll
  for (int j = 0; j < 32; j += 8)
    dst[(size_t)(c0 + ty + j) * R + r0 + tx] = (_Float16)t[tx][ty + j];
}

// ---------------- GEMM1: x @ W1 fused with gate math ----------------
// r7: staging-BW-bound regime identified. r5 (BM=128) hit 38% MfmaUtil =
// exactly the L2->LDS BW ceiling for intensity (8+12)KB/1.57MFLOP; r6
// (BM=64) doubled B-staging per FLOP -> 29% (both match 65 B/cyc/CU model).
// Fix: BM=256 -> intensity (16+12)KB/3.14MFLOP, predicted ceiling ~55%.
// 512 threads, 8 waves (4m x 2n), wave tile 64x32x3g (acc 96 + frags 40
// VGPR -> 2 waves/SIMD = 8 waves/CU, which r5 proved reaches the BW
// ceiling). LDS: A ring-3 (3x16KB) + B ring-2 (2x12KB) = 72KB.
// Staging split: waves 0-3 stage B (3 gloads: one 16-row chunk per gate),
// ALL waves stage A (2 gloads). Per-step: [wait vmcnt(2)] [barrier]
// [stage B(t+1), A(t+2)] [ds_read t] [24 MFMA]. Queue sim (B-waves):
// ...[A(t+1)x2] +issue[B(t+1)x3,A(t+2)x2] -> wait(2) completes A(t+1),
// B(t+1)... wait, completes through B(t+1)? No: keeps 2 youngest =
// A(t+2)x2, completes A(t+1) & B(t+1)&older -- B needs completion at its
// READ step which is the NEXT wait; verified: B(t) read at step t was
// completed by step t's wait. A-only waves: queue [A(t+1)x2,A(t+2)x2],
// wait(2) completes A(t+1) ✓ -- SAME vmcnt(2) for both classes.
// WAR-safe as r5 (stage targets' readers passed the preceding barrier).
// Tail steps stage dummy loads <=2.2KB past xh/w1t into adjacent ws ✓.
//
// LDS swizzle: per-row k-group XOR swz(r)=(r>>1)&3 on the GLOBAL source
// address (gload_lds dest linear); conflict-free b128 (r2: conflicts=0).
// Block order: NATURAL raster (r2: XCD remap tripled HBM FETCH).
__global__ __launch_bounds__(512, 2) void gemm1_fused(
    const _Float16* __restrict__ xh, const _Float16* __restrict__ w1t,
    const float* __restrict__ b1, uint32_t* __restrict__ zg) {
  __shared__ _Float16 As[3][256 * 32];      // 3 x 16KB = 48KB
  __shared__ _Float16 Bs[2][3][64 * 32];    // 2 x 12KB = 24KB ; 72KB total

  const int tid = threadIdx.x;
  const int wave = tid >> 6, lane = tid & 63;
  const int wm = wave >> 1, wn = wave & 1;     // 4x2 waves: 64 rows x 32 cols/gate
  const int m0 = blockIdx.y * 256;
  const int d0 = blockIdx.x * 64;
  const int lrow = lane >> 2;                              // staged row in 16-row chunk
  const int lk = (((lane & 3) ^ ((lrow >> 1) & 3)) * 8);   // staged k offset (halfs)
  const int roff = ((((lane & 15) << 2) | ((lane >> 4) ^ ((lane >> 1) & 3))) * 8); // read offset
  const bool bstage = (wave < 4);

  const _Float16* pA0 = xh + (size_t)(m0 + wave * 32 + lrow) * K1 + lk;
  const _Float16* pA1 = pA0 + (size_t)16 * K1;
  const _Float16* pB0 = w1t + (size_t)(d0 + (wave & 3) * 16 + lrow) * K1 + lk;
  const _Float16* pB1 = pB0 + (size_t)DIN * K1;
  const _Float16* pB2 = pB1 + (size_t)DIN * K1;

  floatx4 acc[3][4][2] = {};

  // prologue: [B(0)x3 (waves 0-3)], A(0)x2, A(1)x2
  if (bstage) {
    gload16(pB0, &Bs[0][0][wave * 512]);
    gload16(pB1, &Bs[0][1][wave * 512]);
    gload16(pB2, &Bs[0][2][wave * 512]);
  }
  gload16(pA0, &As[0][(wave * 2 + 0) * 512]);
  gload16(pA1, &As[0][(wave * 2 + 1) * 512]);
  gload16(pA0 + 32, &As[1][(wave * 2 + 0) * 512]);
  gload16(pA1 + 32, &As[1][(wave * 2 + 1) * 512]);
  pB0 += 32; pB1 += 32; pB2 += 32;   // -> tile 1
  pA0 += 64; pA1 += 64;              // -> tile 2

#define G1_STEP(rbA, sbA, rbB, sbB)                                             \
  do {                                                                          \
    asm volatile("s_waitcnt vmcnt(2)" ::: "memory");                            \
    __builtin_amdgcn_s_barrier();                                               \
    asm volatile("" ::: "memory");                                              \
    if (bstage) {                                                               \
      gload16(pB0, &Bs[sbB][0][wave * 512]);                                    \
      gload16(pB1, &Bs[sbB][1][wave * 512]);                                    \
      gload16(pB2, &Bs[sbB][2][wave * 512]);                                    \
    }                                                                           \
    gload16(pA0, &As[sbA][(wave * 2 + 0) * 512]);                               \
    gload16(pA1, &As[sbA][(wave * 2 + 1) * 512]);                               \
    pA0 += 32; pA1 += 32; pB0 += 32; pB1 += 32; pB2 += 32;                      \
    half8 af[4], bfr[3][2];                                                     \
    _Pragma("unroll")                                                           \
    for (int mi = 0; mi < 4; ++mi)                                              \
      af[mi] = *(const half8*)(&As[rbA][(wm * 4 + mi) * 512 + roff]);           \
    _Pragma("unroll")                                                           \
    for (int gt = 0; gt < 3; ++gt)                                              \
      _Pragma("unroll")                                                         \
      for (int ni = 0; ni < 2; ++ni)                                            \
        bfr[gt][ni] = *(const half8*)(&Bs[rbB][gt][(wn * 2 + ni) * 512 + roff]);\
    _Pragma("unroll")                                                           \
    for (int gt = 0; gt < 3; ++gt)                                              \
      _Pragma("unroll")                                                         \
      for (int mi = 0; mi < 4; ++mi)                                            \
        _Pragma("unroll")                                                       \
        for (int ni = 0; ni < 2; ++ni)                                          \
          acc[gt][mi][ni] = __builtin_amdgcn_mfma_f32_16x16x32_f16(             \
              af[mi], bfr[gt][ni], acc[gt][mi][ni], 0, 0, 0);                   \
  } while (0)

  // 32 K-tiles; tile t reads As[t%3], Bs[t&1]; stages A(t+2)->(t+2)%3,
  // B(t+1)->(t+1)&1. Pattern period lcm(3,2)=6; 32 = 5*6 + 2.
  for (int it6 = 0; it6 < 5; ++it6) {
    G1_STEP(0, 2, 0, 1);
    G1_STEP(1, 0, 1, 0);
    G1_STEP(2, 1, 0, 1);
    G1_STEP(0, 2, 1, 0);
    G1_STEP(1, 0, 0, 1);
    G1_STEP(2, 1, 1, 0);
  }
  G1_STEP(0, 2, 0, 1);   // t=30
  G1_STEP(1, 0, 1, 0);   // t=31
#undef G1_STEP

  // epilogue: bias + gate math, write packed (z,g)
  // z = sigma(softplus(-f)-softplus(-i)) = u/(u+v), u=1+e^-f, v=1+e^-i
#pragma unroll
  for (int ni = 0; ni < 2; ++ni) {
    int d = d0 + wn * 32 + ni * 16 + (lane & 15);
    float bh = b1[d], bf_ = b1[DIN + d], bi = b1[2 * DIN + d];
#pragma unroll
    for (int mi = 0; mi < 4; ++mi) {
#pragma unroll
      for (int r = 0; r < 4; ++r) {
        int m = m0 + wm * 64 + mi * 16 + (lane >> 4) * 4 + r;
        float hv = acc[0][mi][ni][r] + bh;
        float fv = acc[1][mi][ni][r] + bf_;
        float iv = acc[2][mi][ni][r] + bi;
        float u = 1.f + __expf(-fminf(fmaxf(fv, -30.f), 30.f));
        float v = 1.f + __expf(-fminf(fmaxf(iv, -30.f), 30.f));
        float z = __fdividef(u, u + v);
        float gg = (hv >= 0.f) ? (hv + 0.5f)
                               : __fdividef(1.f, 1.f + __expf(-fmaxf(hv, -30.f)));
        zg[(size_t)m * DIN + d] = hbits(z) | (hbits(gg) << 16);
      }
    }
  }
}

// ---------------- chunked parallel scan: h_t = (1-z) h + z g ----------------

__global__ void scanA(const uint32_t* __restrict__ zg,
                      float* __restrict__ cA, float* __restrict__ cB) {
  int gidx = blockIdx.x * 256 + threadIdx.x;
  int q = gidx >> 13, c = gidx & (NCH - 1);
  int b = c >> 11, d = c & (DIN - 1);
  size_t base = ((size_t)b * SS + q * CLEN) * DIN + d;
  float A = 1.f, Bv = 0.f;
#pragma unroll 4
  for (int t = 0; t < CLEN; ++t) {
    uint32_t v = zg[base + (size_t)t * DIN];
    float z = h_lo(v), g = h_hi(v);
    A *= (1.f - z);
    Bv = fmaf(z, g - Bv, Bv);
  }
  cA[q * NCH + c] = A;
  cB[q * NCH + c] = Bv;
}

__global__ void scanB(const float* __restrict__ cA, const float* __restrict__ cB,
                      const float* __restrict__ init_h, float* __restrict__ cH) {
  int c = blockIdx.x * 256 + threadIdx.x;  // 8192 channels
  int d = c & (DIN - 1);
  float x = init_h[d];
  float h = (x >= 0.f) ? (x + 0.5f) : sigm(x);  // h0 = g(init_h)
#pragma unroll
  for (int q = 0; q < NCHUNK; ++q) {
    cH[q * NCH + c] = h;                        // h at START of chunk q
    h = fmaf(cA[q * NCH + c], h, cB[q * NCH + c]);
  }
}

__global__ void scanC(const uint32_t* __restrict__ zg, const float* __restrict__ cH,
                      _Float16* __restrict__ hh, float* __restrict__ out_tail) {
  int gidx = blockIdx.x * 256 + threadIdx.x;
  int q = gidx >> 13, c = gidx & (NCH - 1);
  int b = c >> 11, d = c & (DIN - 1);
  size_t base = ((size_t)b * SS + q * CLEN) * DIN + d;
  float h = cH[q * NCH + c];
#pragma unroll 4
  for (int t = 0; t < CLEN; ++t) {
    uint32_t v = zg[base + (size_t)t * DIN];
    float z = h_lo(v), g = h_hi(v);
    h = fmaf(z, g - h, h);
    hh[base + (size_t)t * DIN] = (_Float16)h;
  }
  if (q == NCHUNK - 1) {
    out_tail[c] = h;             // next_hidden
    out_tail[NCH + c] = logf(h); // next_log_hidden
  }
}

// ---------------- GEMM2: out_h @ W2 + b2 (256x128, ring-pipelined) ---------
// r7: BM=256 for staging intensity (see gemm1). 512 threads, 8 waves
// (4m x 2n), wave tile 64x64: acc 64 + frags 32 VGPR ->
// __launch_bounds__(512,4) pins <=128 -> 2 blocks/CU (16 waves). LDS:
// A ring-3 (48KB) + B ring-2 (16KB) = 64KB -> 2 blocks = 128KB ✓.
// Uniform staging: every wave 2 A + 1 B gloads/step; wait vmcnt(2)
// (same queue sim as gemm1: completes A(t),B(t) by read time, keeps
// A(t+2) pair in flight). Natural raster order.
__global__ __launch_bounds__(512, 4) void gemm2k(
    const _Float16* __restrict__ hh, const _Float16* __restrict__ w2t,
    const float* __restrict__ b2, float* __restrict__ out) {
  __shared__ _Float16 As[3][256 * 32];   // 3 x 16KB = 48KB
  __shared__ _Float16 Bs[2][128 * 32];   // 2 x 8KB  = 16KB ; 64KB total

  const int tid = threadIdx.x;
  const int wave = tid >> 6, lane = tid & 63;
  const int wm = wave >> 1, wn = wave & 1;     // 4x2 waves: 64x64 each
  const int m0 = blockIdx.y * 256;
  const int n0 = blockIdx.x * 128;
  const int lrow = lane >> 2;
  const int lk = (((lane & 3) ^ ((lrow >> 1) & 3)) * 8);   // conflict-free swz (see gemm1)
  const int roff = ((((lane & 15) << 2) | ((lane >> 4) ^ ((lane >> 1) & 3))) * 8);

  const _Float16* pA0 = hh + (size_t)(m0 + wave * 32 + lrow) * K2 + lk;
  const _Float16* pA1 = pA0 + (size_t)16 * K2;
  const _Float16* pB0 = w2t + (size_t)(n0 + wave * 16 + lrow) * K2 + lk;

  floatx4 acc[4][4] = {};

  // prologue: B(0), A(0)x2, A(1)x2  (5 outstanding)
  gload16(pB0, &Bs[0][wave * 512]);
  gload16(pA0, &As[0][(wave * 2 + 0) * 512]);
  gload16(pA1, &As[0][(wave * 2 + 1) * 512]);
  gload16(pA0 + 32, &As[1][(wave * 2 + 0) * 512]);
  gload16(pA1 + 32, &As[1][(wave * 2 + 1) * 512]);
  pB0 += 32;            // -> tile 1
  pA0 += 64; pA1 += 64; // -> tile 2

#define G2_STEP(rbA, sbA, rbB, sbB)                                             \
  do {                                                                          \
    asm volatile("s_waitcnt vmcnt(2)" ::: "memory");                            \
    __builtin_amdgcn_s_barrier();                                               \
    asm volatile("" ::: "memory");                                              \
    gload16(pB0, &Bs[sbB][wave * 512]);                                         \
    gload16(pA0, &As[sbA][(wave * 2 + 0) * 512]);                               \
    gload16(pA1, &As[sbA][(wave * 2 + 1) * 512]);                               \
    pA0 += 32; pA1 += 32; pB0 += 32;                                            \
    half8 af[4], bfr[4];                                                        \
    _Pragma("unroll")                                                           \
    for (int mi = 0; mi < 4; ++mi)                                              \
      af[mi] = *(const half8*)(&As[rbA][(wm * 4 + mi) * 512 + roff]);           \
    _Pragma("unroll")                                                           \
    for (int ni = 0; ni < 4; ++ni)                                              \
      bfr[ni] = *(const half8*)(&Bs[rbB][(wn * 4 + ni) * 512 + roff]);          \
    _Pragma("unroll")                                                           \
    for (int mi = 0; mi < 4; ++mi)                                              \
      _Pragma("unroll")                                                         \
      for (int ni = 0; ni < 4; ++ni)                                            \
        acc[mi][ni] = __builtin_amdgcn_mfma_f32_16x16x32_f16(                   \
            af[mi], bfr[ni], acc[mi][ni], 0, 0, 0);                             \
  } while (0)

  // 64 K-tiles; tile t reads As[t%3], Bs[t&1]; stages A(t+2), B(t+1).
  // Period 6; 64 = 10*6 + 4.
  for (int it6 = 0; it6 < 10; ++it6) {
    G2_STEP(0, 2, 0, 1);
    G2_STEP(1, 0, 1, 0);
    G2_STEP(2, 1, 0, 1);
    G2_STEP(0, 2, 1, 0);
    G2_STEP(1, 0, 0, 1);
    G2_STEP(2, 1, 1, 0);
  }
  G2_STEP(0, 2, 0, 1);   // t=60
  G2_STEP(1, 0, 1, 0);   // t=61
  G2_STEP(2, 1, 0, 1);   // t=62
  G2_STEP(0, 2, 1, 0);   // t=63
#undef G2_STEP

#pragma unroll
  for (int ni = 0; ni < 4; ++ni) {
    int n = n0 + wn * 64 + ni * 16 + (lane & 15);
    float bias = b2[n];
#pragma unroll
    for (int mi = 0; mi < 4; ++mi) {
#pragma unroll
      for (int r = 0; r < 4; ++r) {
        int m = m0 + wm * 64 + mi * 16 + (lane >> 4) * 4 + r;
        out[(size_t)m * N2 + n] = acc[mi][ni][r] + bias;
      }
    }
  }
}

// ---------------- launch ----------------

extern "C" void kernel_launch(void* const* d_in, const int* in_sizes, int n_in,
                              void* d_out, int out_size, void* d_ws, size_t ws_size,
                              hipStream_t stream) {
  const float* x      = (const float*)d_in[0];
  const float* W1     = (const float*)d_in[1];
  const float* b1     = (const float*)d_in[2];
  const float* W2     = (const float*)d_in[3];
  const float* b2     = (const float*)d_in[4];
  const float* init_h = (const float*)d_in[5];
  float* out = (float*)d_out;

  char* w = (char*)d_ws;
  _Float16* xh  = (_Float16*)w; w += (size_t)MTOT * K1 * 2;       // 32 MB
  _Float16* w1t = (_Float16*)w; w += (size_t)3 * DIN * K1 * 2;    // 12 MB
  _Float16* w2t = (_Float16*)w; w += (size_t)N2 * K2 * 2;         // 4 MB
  uint32_t* zg  = (uint32_t*)w; w += (size_t)MTOT * DIN * 4;      // 128 MB
  _Float16* hh  = (_Float16*)w; w += (size_t)MTOT * DIN * 2;      // 64 MB
  float* cA = (float*)w; w += (size_t)NCH * NCHUNK * 4;
  float* cB = (float*)w; w += (size_t)NCH * NCHUNK * 4;
  float* cH = (float*)w; w += (size_t)NCH * NCHUNK * 4;

  f32_to_f16_vec<<<dim3(MTOT * K1 / 1024), dim3(256), 0, stream>>>(x, xh);
  transpose_cvt<<<dim3(3 * DIN / 32, K1 / 32), dim3(32, 8), 0, stream>>>(W1, w1t, K1, 3 * DIN);
  transpose_cvt<<<dim3(N2 / 32, K2 / 32), dim3(32, 8), 0, stream>>>(W2, w2t, K2, N2);

  gemm1_fused<<<dim3(DIN / 64, MTOT / 256), dim3(512), 0, stream>>>(xh, w1t, b1, zg);

  scanA<<<dim3(NCH * NCHUNK / 256), dim3(256), 0, stream>>>(zg, cA, cB);
  scanB<<<dim3(NCH / 256), dim3(256), 0, stream>>>(cA, cB, init_h, cH);
  scanC<<<dim3(NCH * NCHUNK / 256), dim3(256), 0, stream>>>(zg, cH, hh, out + (size_t)MTOT * DD);

  gemm2k<<<dim3(N2 / 128, MTOT / 256), dim3(512), 0, stream>>>(hh, w2t, b2, out);
}

// Round 8
// 539.145 us; speedup vs baseline: 1.1195x; 1.0035x over previous
//
#include <hip/hip_runtime.h>
#include <cstdint>
#include <cstddef>

// Problem constants (B=4, S=4096, D=1024, Din=2048)
#define BB 4
#define SS 4096
#define DD 1024
#define DIN 2048
#define MTOT (BB*SS)        // 16384 rows
#define K1 DD               // GEMM1 K = 1024
#define K2 DIN              // GEMM2 K = 2048
#define N2 DD               // GEMM2 N = 1024
#define NCH (BB*DIN)        // 8192 scan channels
#define NCHUNK 32
#define CLEN (SS/NCHUNK)    // 128

typedef _Float16 half8  __attribute__((ext_vector_type(8)));
typedef _Float16 half4v __attribute__((ext_vector_type(4)));
typedef float    floatx4 __attribute__((ext_vector_type(4)));

#define AS1(p) ((__attribute__((address_space(1))) void*)(uintptr_t)(p))
#define AS3(p) ((__attribute__((address_space(3))) void*)(uint32_t)(uintptr_t)(p))

__device__ __forceinline__ void gload16(const void* g, void* l) {
  // async global->LDS, 16B/lane; LDS dest = wave-uniform base + lane*16
  __builtin_amdgcn_global_load_lds(AS1(g), AS3(l), 16, 0, 0);
}

__device__ __forceinline__ float sigm(float x) { return 1.f / (1.f + __expf(-x)); }
__device__ __forceinline__ uint32_t hbits(float f) {
  _Float16 h = (_Float16)f; uint16_t u; __builtin_memcpy(&u, &h, 2); return (uint32_t)u;
}
__device__ __forceinline__ float h_lo(uint32_t v) {
  uint16_t u = (uint16_t)(v & 0xffffu); _Float16 h; __builtin_memcpy(&h, &u, 2); return (float)h;
}
__device__ __forceinline__ float h_hi(uint32_t v) {
  uint16_t u = (uint16_t)(v >> 16); _Float16 h; __builtin_memcpy(&h, &u, 2); return (float)h;
}

// ---------------- elementwise converts ----------------

__global__ void f32_to_f16_vec(const float* __restrict__ src, _Float16* __restrict__ dst) {
  int i = (blockIdx.x * blockDim.x + threadIdx.x) * 4;
  float4 v = *(const float4*)(src + i);
  half4v o; o.x = (_Float16)v.x; o.y = (_Float16)v.y; o.z = (_Float16)v.z; o.w = (_Float16)v.w;
  *(half4v*)(dst + i) = o;
}

// src[R][C] f32 -> dst[C][R] f16
__global__ void transpose_cvt(const float* __restrict__ src, _Float16* __restrict__ dst,
                              int R, int C) {
  __shared__ float t[32][33];
  int c0 = blockIdx.x * 32, r0 = blockIdx.y * 32;
  int tx = threadIdx.x, ty = threadIdx.y;
#pragma unroll
  for (int j = 0; j < 32; j += 8)
    t[ty + j][tx] = src[(size_t)(r0 + ty + j) * C + c0 + tx];
  __syncthreads();
#pragma unroll
  for (int j = 0; j < 32; j += 8)
    dst[(size_t)(c0 + ty + j) * R + r0 + tx] = (_Float16)t[tx][ty + j];
}

// ---------------- GEMM1: x @ W1 fused with gate math ----------------
// r8: 2-phase K-step (T3-minimum + T5). r7 budget: MFMA pipe 45% and LDS
// pipe 44% both half-idle, alternating not overlapping (1 barrier/step,
// 2 waves/SIMD lockstep). Phase split by m-half: phase0 = {vmcnt, barrier,
// stage B(t+1), read af[0..1]+bfr x6, setprio(1), 12 MFMA, setprio(0)};
// mid s_barrier; phase1 = {stage A(t+2), read af[2..3], setprio(1),
// 12 MFMA, setprio(0)}. LDS bursts of phase p overlap matrix-pipe drain
// of phase p-1 across waves. Per-wave VMEM issue order (B x3 then A x2)
// unchanged -> vmcnt(2) accounting identical to r7 (verified queue sim:
// completes A(t)/B(t) by their read step, keeps A(t+2) pair in flight;
// A-only waves same). Mid-barrier hazards: phase1 reads As[rbA]!=As[sbA];
// As[sbA]'s prior readers (tile t-1) completed before this step's top
// barrier -- same WAR argument as r7. No inline lgkmcnt (compiler inserts
// exact waits; avoids rule-#18 hoist hazard).
//
// BM=256 (r7): staging intensity halved vs BM=128 -> FETCH 185MB.
// Asymmetric ring: A ring-3 (3x16KB, dist 2), B ring-2 (2x12KB, dist 1).
// Tail steps stage dummy loads <=2.2KB past xh/w1t into adjacent ws ✓.
// LDS swizzle: per-row k-group XOR swz(r)=(r>>1)&3 on the GLOBAL source
// address (gload_lds dest linear); conflict-free b128 (r2: conflicts=0).
// Block order: NATURAL raster (r2: XCD remap tripled HBM FETCH).
__global__ __launch_bounds__(512, 2) void gemm1_fused(
    const _Float16* __restrict__ xh, const _Float16* __restrict__ w1t,
    const float* __restrict__ b1, uint32_t* __restrict__ zg) {
  __shared__ _Float16 As[3][256 * 32];      // 3 x 16KB = 48KB
  __shared__ _Float16 Bs[2][3][64 * 32];    // 2 x 12KB = 24KB ; 72KB total

  const int tid = threadIdx.x;
  const int wave = tid >> 6, lane = tid & 63;
  const int wm = wave >> 1, wn = wave & 1;     // 4x2 waves: 64 rows x 32 cols/gate
  const int m0 = blockIdx.y * 256;
  const int d0 = blockIdx.x * 64;
  const int lrow = lane >> 2;                              // staged row in 16-row chunk
  const int lk = (((lane & 3) ^ ((lrow >> 1) & 3)) * 8);   // staged k offset (halfs)
  const int roff = ((((lane & 15) << 2) | ((lane >> 4) ^ ((lane >> 1) & 3))) * 8); // read offset
  const bool bstage = (wave < 4);

  const _Float16* pA0 = xh + (size_t)(m0 + wave * 32 + lrow) * K1 + lk;
  const _Float16* pA1 = pA0 + (size_t)16 * K1;
  const _Float16* pB0 = w1t + (size_t)(d0 + (wave & 3) * 16 + lrow) * K1 + lk;
  const _Float16* pB1 = pB0 + (size_t)DIN * K1;
  const _Float16* pB2 = pB1 + (size_t)DIN * K1;

  floatx4 acc[3][4][2] = {};

  // prologue: [B(0)x3 (waves 0-3)], A(0)x2, A(1)x2
  if (bstage) {
    gload16(pB0, &Bs[0][0][wave * 512]);
    gload16(pB1, &Bs[0][1][wave * 512]);
    gload16(pB2, &Bs[0][2][wave * 512]);
  }
  gload16(pA0, &As[0][(wave * 2 + 0) * 512]);
  gload16(pA1, &As[0][(wave * 2 + 1) * 512]);
  gload16(pA0 + 32, &As[1][(wave * 2 + 0) * 512]);
  gload16(pA1 + 32, &As[1][(wave * 2 + 1) * 512]);
  pB0 += 32; pB1 += 32; pB2 += 32;   // -> tile 1
  pA0 += 64; pA1 += 64;              // -> tile 2

#define G1_STEP(rbA, sbA, rbB, sbB)                                             \
  do {                                                                          \
    asm volatile("s_waitcnt vmcnt(2)" ::: "memory");                            \
    __builtin_amdgcn_s_barrier();                                               \
    asm volatile("" ::: "memory");                                              \
    if (bstage) {                                                               \
      gload16(pB0, &Bs[sbB][0][wave * 512]);                                    \
      gload16(pB1, &Bs[sbB][1][wave * 512]);                                    \
      gload16(pB2, &Bs[sbB][2][wave * 512]);                                    \
    }                                                                           \
    half8 af[4], bfr[3][2];                                                     \
    af[0] = *(const half8*)(&As[rbA][(wm * 4 + 0) * 512 + roff]);               \
    af[1] = *(const half8*)(&As[rbA][(wm * 4 + 1) * 512 + roff]);               \
    _Pragma("unroll")                                                           \
    for (int gt = 0; gt < 3; ++gt)                                              \
      _Pragma("unroll")                                                         \
      for (int ni = 0; ni < 2; ++ni)                                            \
        bfr[gt][ni] = *(const half8*)(&Bs[rbB][gt][(wn * 2 + ni) * 512 + roff]);\
    __builtin_amdgcn_s_setprio(1);                                              \
    _Pragma("unroll")                                                           \
    for (int gt = 0; gt < 3; ++gt)                                              \
      _Pragma("unroll")                                                         \
      for (int mi = 0; mi < 2; ++mi)                                            \
        _Pragma("unroll")                                                       \
        for (int ni = 0; ni < 2; ++ni)                                          \
          acc[gt][mi][ni] = __builtin_amdgcn_mfma_f32_16x16x32_f16(             \
              af[mi], bfr[gt][ni], acc[gt][mi][ni], 0, 0, 0);                   \
    __builtin_amdgcn_s_setprio(0);                                              \
    __builtin_amdgcn_s_barrier();                                               \
    asm volatile("" ::: "memory");                                              \
    gload16(pA0, &As[sbA][(wave * 2 + 0) * 512]);                               \
    gload16(pA1, &As[sbA][(wave * 2 + 1) * 512]);                               \
    pA0 += 32; pA1 += 32; pB0 += 32; pB1 += 32; pB2 += 32;                      \
    af[2] = *(const half8*)(&As[rbA][(wm * 4 + 2) * 512 + roff]);               \
    af[3] = *(const half8*)(&As[rbA][(wm * 4 + 3) * 512 + roff]);               \
    __builtin_amdgcn_s_setprio(1);                                              \
    _Pragma("unroll")                                                           \
    for (int gt = 0; gt < 3; ++gt)                                              \
      _Pragma("unroll")                                                         \
      for (int mi = 2; mi < 4; ++mi)                                            \
        _Pragma("unroll")                                                       \
        for (int ni = 0; ni < 2; ++ni)                                          \
          acc[gt][mi][ni] = __builtin_amdgcn_mfma_f32_16x16x32_f16(             \
              af[mi], bfr[gt][ni], acc[gt][mi][ni], 0, 0, 0);                   \
    __builtin_amdgcn_s_setprio(0);                                              \
  } while (0)

  // 32 K-tiles; tile t reads As[t%3], Bs[t&1]; stages A(t+2)->(t+2)%3,
  // B(t+1)->(t+1)&1. Pattern period lcm(3,2)=6; 32 = 5*6 + 2.
  for (int it6 = 0; it6 < 5; ++it6) {
    G1_STEP(0, 2, 0, 1);
    G1_STEP(1, 0, 1, 0);
    G1_STEP(2, 1, 0, 1);
    G1_STEP(0, 2, 1, 0);
    G1_STEP(1, 0, 0, 1);
    G1_STEP(2, 1, 1, 0);
  }
  G1_STEP(0, 2, 0, 1);   // t=30
  G1_STEP(1, 0, 1, 0);   // t=31
#undef G1_STEP

  // epilogue: bias + gate math, write packed (z,g)
  // z = sigma(softplus(-f)-softplus(-i)) = u/(u+v), u=1+e^-f, v=1+e^-i
#pragma unroll
  for (int ni = 0; ni < 2; ++ni) {
    int d = d0 + wn * 32 + ni * 16 + (lane & 15);
    float bh = b1[d], bf_ = b1[DIN + d], bi = b1[2 * DIN + d];
#pragma unroll
    for (int mi = 0; mi < 4; ++mi) {
#pragma unroll
      for (int r = 0; r < 4; ++r) {
        int m = m0 + wm * 64 + mi * 16 + (lane >> 4) * 4 + r;
        float hv = acc[0][mi][ni][r] + bh;
        float fv = acc[1][mi][ni][r] + bf_;
        float iv = acc[2][mi][ni][r] + bi;
        float u = 1.f + __expf(-fminf(fmaxf(fv, -30.f), 30.f));
        float v = 1.f + __expf(-fminf(fmaxf(iv, -30.f), 30.f));
        float z = __fdividef(u, u + v);
        float gg = (hv >= 0.f) ? (hv + 0.5f)
                               : __fdividef(1.f, 1.f + __expf(-fmaxf(hv, -30.f)));
        zg[(size_t)m * DIN + d] = hbits(z) | (hbits(gg) << 16);
      }
    }
  }
}

// ---------------- chunked parallel scan: h_t = (1-z) h + z g ----------------

__global__ void scanA(const uint32_t* __restrict__ zg,
                      float* __restrict__ cA, float* __restrict__ cB) {
  int gidx = blockIdx.x * 256 + threadIdx.x;
  int q = gidx >> 13, c = gidx & (NCH - 1);
  int b = c >> 11, d = c & (DIN - 1);
  size_t base = ((size_t)b * SS + q * CLEN) * DIN + d;
  float A = 1.f, Bv = 0.f;
#pragma unroll 4
  for (int t = 0; t < CLEN; ++t) {
    uint32_t v = zg[base + (size_t)t * DIN];
    float z = h_lo(v), g = h_hi(v);
    A *= (1.f - z);
    Bv = fmaf(z, g - Bv, Bv);
  }
  cA[q * NCH + c] = A;
  cB[q * NCH + c] = Bv;
}

__global__ void scanB(const float* __restrict__ cA, const float* __restrict__ cB,
                      const float* __restrict__ init_h, float* __restrict__ cH) {
  int c = blockIdx.x * 256 + threadIdx.x;  // 8192 channels
  int d = c & (DIN - 1);
  float x = init_h[d];
  float h = (x >= 0.f) ? (x + 0.5f) : sigm(x);  // h0 = g(init_h)
#pragma unroll
  for (int q = 0; q < NCHUNK; ++q) {
    cH[q * NCH + c] = h;                        // h at START of chunk q
    h = fmaf(cA[q * NCH + c], h, cB[q * NCH + c]);
  }
}

__global__ void scanC(const uint32_t* __restrict__ zg, const float* __restrict__ cH,
                      _Float16* __restrict__ hh, float* __restrict__ out_tail) {
  int gidx = blockIdx.x * 256 + threadIdx.x;
  int q = gidx >> 13, c = gidx & (NCH - 1);
  int b = c >> 11, d = c & (DIN - 1);
  size_t base = ((size_t)b * SS + q * CLEN) * DIN + d;
  float h = cH[q * NCH + c];
#pragma unroll 4
  for (int t = 0; t < CLEN; ++t) {
    uint32_t v = zg[base + (size_t)t * DIN];
    float z = h_lo(v), g = h_hi(v);
    h = fmaf(z, g - h, h);
    hh[base + (size_t)t * DIN] = (_Float16)h;
  }
  if (q == NCHUNK - 1) {
    out_tail[c] = h;             // next_hidden
    out_tail[NCH + c] = logf(h); // next_log_hidden
  }
}

// ---------------- GEMM2: out_h @ W2 + b2 (256x128, 2-phase) ----------------
// Same 2-phase structure as gemm1 (see comment there). Per-wave VMEM issue
// order (B x1 then A x2) unchanged -> vmcnt(2) as r7. LDS: A ring-3 (48KB)
// + B ring-2 (16KB) = 64KB. Natural raster order.
__global__ __launch_bounds__(512, 4) void gemm2k(
    const _Float16* __restrict__ hh, const _Float16* __restrict__ w2t,
    const float* __restrict__ b2, float* __restrict__ out) {
  __shared__ _Float16 As[3][256 * 32];   // 3 x 16KB = 48KB
  __shared__ _Float16 Bs[2][128 * 32];   // 2 x 8KB  = 16KB ; 64KB total

  const int tid = threadIdx.x;
  const int wave = tid >> 6, lane = tid & 63;
  const int wm = wave >> 1, wn = wave & 1;     // 4x2 waves: 64x64 each
  const int m0 = blockIdx.y * 256;
  const int n0 = blockIdx.x * 128;
  const int lrow = lane >> 2;
  const int lk = (((lane & 3) ^ ((lrow >> 1) & 3)) * 8);   // conflict-free swz (see gemm1)
  const int roff = ((((lane & 15) << 2) | ((lane >> 4) ^ ((lane >> 1) & 3))) * 8);

  const _Float16* pA0 = hh + (size_t)(m0 + wave * 32 + lrow) * K2 + lk;
  const _Float16* pA1 = pA0 + (size_t)16 * K2;
  const _Float16* pB0 = w2t + (size_t)(n0 + wave * 16 + lrow) * K2 + lk;

  floatx4 acc[4][4] = {};

  // prologue: B(0), A(0)x2, A(1)x2  (5 outstanding)
  gload16(pB0, &Bs[0][wave * 512]);
  gload16(pA0, &As[0][(wave * 2 + 0) * 512]);
  gload16(pA1, &As[0][(wave * 2 + 1) * 512]);
  gload16(pA0 + 32, &As[1][(wave * 2 + 0) * 512]);
  gload16(pA1 + 32, &As[1][(wave * 2 + 1) * 512]);
  pB0 += 32;            // -> tile 1
  pA0 += 64; pA1 += 64; // -> tile 2

#define G2_STEP(rbA, sbA, rbB, sbB)                                             \
  do {                                                                          \
    asm volatile("s_waitcnt vmcnt(2)" ::: "memory");                            \
    __builtin_amdgcn_s_barrier();                                               \
    asm volatile("" ::: "memory");                                              \
    gload16(pB0, &Bs[sbB][wave * 512]);                                         \
    half8 af[4], bfr[4];                                                        \
    af[0] = *(const half8*)(&As[rbA][(wm * 4 + 0) * 512 + roff]);               \
    af[1] = *(const half8*)(&As[rbA][(wm * 4 + 1) * 512 + roff]);               \
    _Pragma("unroll")                                                           \
    for (int ni = 0; ni < 4; ++ni)                                              \
      bfr[ni] = *(const half8*)(&Bs[rbB][(wn * 4 + ni) * 512 + roff]);          \
    __builtin_amdgcn_s_setprio(1);                                              \
    _Pragma("unroll")                                                           \
    for (int mi = 0; mi < 2; ++mi)                                              \
      _Pragma("unroll")                                                         \
      for (int ni = 0; ni < 4; ++ni)                                            \
        acc[mi][ni] = __builtin_amdgcn_mfma_f32_16x16x32_f16(                   \
            af[mi], bfr[ni], acc[mi][ni], 0, 0, 0);                             \
    __builtin_amdgcn_s_setprio(0);                                              \
    __builtin_amdgcn_s_barrier();                                               \
    asm volatile("" ::: "memory");                                              \
    gload16(pA0, &As[sbA][(wave * 2 + 0) * 512]);                               \
    gload16(pA1, &As[sbA][(wave * 2 + 1) * 512]);                               \
    pA0 += 32; pA1 += 32; pB0 += 32;                                            \
    af[2] = *(const half8*)(&As[rbA][(wm * 4 + 2) * 512 + roff]);               \
    af[3] = *(const half8*)(&As[rbA][(wm * 4 + 3) * 512 + roff]);               \
    __builtin_amdgcn_s_setprio(1);                                              \
    _Pragma("unroll")                                                           \
    for (int mi = 2; mi < 4; ++mi)                                              \
      _Pragma("unroll")                                                         \
      for (int ni = 0; ni < 4; ++ni)                                            \
        acc[mi][ni] = __builtin_amdgcn_mfma_f32_16x16x32_f16(                   \
            af[mi], bfr[ni], acc[mi][ni], 0, 0, 0);                             \
    __builtin_amdgcn_s_setprio(0);                                              \
  } while (0)

  // 64 K-tiles; tile t reads As[t%3], Bs[t&1]; stages A(t+2), B(t+1).
  // Period 6; 64 = 10*6 + 4.
  for (int it6 = 0; it6 < 10; ++it6) {
    G2_STEP(0, 2, 0, 1);
    G2_STEP(1, 0, 1, 0);
    G2_STEP(2, 1, 0, 1);
    G2_STEP(0, 2, 1, 0);
    G2_STEP(1, 0, 0, 1);
    G2_STEP(2, 1, 1, 0);
  }
  G2_STEP(0, 2, 0, 1);   // t=60
  G2_STEP(1, 0, 1, 0);   // t=61
  G2_STEP(2, 1, 0, 1);   // t=62
  G2_STEP(0, 2, 1, 0);   // t=63
#undef G2_STEP

#pragma unroll
  for (int ni = 0; ni < 4; ++ni) {
    int n = n0 + wn * 64 + ni * 16 + (lane & 15);
    float bias = b2[n];
#pragma unroll
    for (int mi = 0; mi < 4; ++mi) {
#pragma unroll
      for (int r = 0; r < 4; ++r) {
        int m = m0 + wm * 64 + mi * 16 + (lane >> 4) * 4 + r;
        out[(size_t)m * N2 + n] = acc[mi][ni][r] + bias;
      }
    }
  }
}

// ---------------- launch ----------------

extern "C" void kernel_launch(void* const* d_in, const int* in_sizes, int n_in,
                              void* d_out, int out_size, void* d_ws, size_t ws_size,
                              hipStream_t stream) {
  const float* x      = (const float*)d_in[0];
  const float* W1     = (const float*)d_in[1];
  const float* b1     = (const float*)d_in[2];
  const float* W2     = (const float*)d_in[3];
  const float* b2     = (const float*)d_in[4];
  const float* init_h = (const float*)d_in[5];
  float* out = (float*)d_out;

  char* w = (char*)d_ws;
  _Float16* xh  = (_Float16*)w; w += (size_t)MTOT * K1 * 2;       // 32 MB
  _Float16* w1t = (_Float16*)w; w += (size_t)3 * DIN * K1 * 2;    // 12 MB
  _Float16* w2t = (_Float16*)w; w += (size_t)N2 * K2 * 2;         // 4 MB
  uint32_t* zg  = (uint32_t*)w; w += (size_t)MTOT * DIN * 4;      // 128 MB
  _Float16* hh  = (_Float16*)w; w += (size_t)MTOT * DIN * 2;      // 64 MB
  float* cA = (float*)w; w += (size_t)NCH * NCHUNK * 4;
  float* cB = (float*)w; w += (size_t)NCH * NCHUNK * 4;
  float* cH = (float*)w; w += (size_t)NCH * NCHUNK * 4;

  f32_to_f16_vec<<<dim3(MTOT * K1 / 1024), dim3(256), 0, stream>>>(x, xh);
  transpose_cvt<<<dim3(3 * DIN / 32, K1 / 32), dim3(32, 8), 0, stream>>>(W1, w1t, K1, 3 * DIN);
  transpose_cvt<<<dim3(N2 / 32, K2 / 32), dim3(32, 8), 0, stream>>>(W2, w2t, K2, N2);

  gemm1_fused<<<dim3(DIN / 64, MTOT / 256), dim3(512), 0, stream>>>(xh, w1t, b1, zg);

  scanA<<<dim3(NCH * NCHUNK / 256), dim3(256), 0, stream>>>(zg, cA, cB);
  scanB<<<dim3(NCH / 256), dim3(256), 0, stream>>>(cA, cB, init_h, cH);
  scanC<<<dim3(NCH * NCHUNK / 256), dim3(256), 0, stream>>>(zg, cH, hh, out + (size_t)MTOT * DD);

  gemm2k<<<dim3(N2 / 128, MTOT / 256), dim3(512), 0, stream>>>(hh, w2t, b2, out);
}